// Round 3
// baseline (313.944 us; speedup 1.0000x reference)
//
#include <hip/hip_runtime.h>
#include <hip/hip_bf16.h>
#include <stdint.h>

#define L_SEQ 2048
#define S_SEQ 2048
#define BATCH 2
#define EMB 1024
#define NH 16
#define HD 64
#define MROWS 4096  // L*B == S*B

typedef __bf16 bf16x8 __attribute__((ext_vector_type(8)));
typedef float f32x4 __attribute__((ext_vector_type(4)));
typedef __hip_bfloat16 bf16;

__device__ __forceinline__ f32x4 mfma16(bf16x8 a, bf16x8 b, f32x4 c) {
    return __builtin_amdgcn_mfma_f32_16x16x32_bf16(a, b, c, 0, 0, 0);
}

// load 8 consecutive fp32, round to bf16, pack into one 16B fragment
__device__ __forceinline__ bf16x8 ld8_cvt(const float* p) {
    const float4 a = *reinterpret_cast<const float4*>(p);
    const float4 b = *reinterpret_cast<const float4*>(p + 4);
    union { bf16x8 v; bf16 h[8]; } u;
    u.h[0] = __float2bfloat16(a.x); u.h[1] = __float2bfloat16(a.y);
    u.h[2] = __float2bfloat16(a.z); u.h[3] = __float2bfloat16(a.w);
    u.h[4] = __float2bfloat16(b.x); u.h[5] = __float2bfloat16(b.y);
    u.h[6] = __float2bfloat16(b.z); u.h[7] = __float2bfloat16(b.w);
    return u.v;
}

// ---------------------------------------------------------------------------
// Fused QKV projection: C[m, n] = X[m,:] . w_in[n,:] + b_in[n]   (fp32 inputs)
// X = query (n<1024), key (1024<=n<2048), value (n>=2048). M=4096, K=1024.
// fp32 global -> bf16 LDS conversion in staging; MFMA in bf16, fp32 accum.
// Epilogue scatters into head-major layouts:
//   Qh[bh][l][d]  (scaled by 1/8), Kh[bh][s][d], Vt[bh][d][s] (transposed!)
// 128x128 tile, BK=32, 256 threads (4 waves, 2x2), 4x4 16x16 acc per wave.
// ---------------------------------------------------------------------------
__global__ __launch_bounds__(256) void qkv_gemm(
    const float* __restrict__ q_in, const float* __restrict__ k_in,
    const float* __restrict__ v_in, const float* __restrict__ w_in,
    const float* __restrict__ b_in,
    bf16* __restrict__ Qh, bf16* __restrict__ Kh, bf16* __restrict__ Vt)
{
    __shared__ alignas(16) bf16 lds_a[128 * 32];
    __shared__ alignas(16) bf16 lds_b[128 * 32];

    const int tid  = threadIdx.x;
    const int lane = tid & 63;
    const int wv   = tid >> 6;
    const int quad = lane >> 4;
    const int lx   = lane & 15;

    const int m0  = blockIdx.x * 128;
    const int n0g = blockIdx.y * 128;         // global col in [0, 3072)
    const int chunk = n0g >> 10;              // 0=Q, 1=K, 2=V
    const float* Aop = (chunk == 0) ? q_in : (chunk == 1) ? k_in : v_in;

    const int wm = (wv >> 1) * 64;
    const int wn = (wv & 1) * 64;

    // staging: 512 8-elem units per 128x32 tile, 2 per thread
    const int ar0 = tid >> 2;
    const int ac0 = (tid & 3) * 8;
    const int ar1 = ar0 + 64;

    f32x4 acc[4][4];
#pragma unroll
    for (int i = 0; i < 4; i++)
#pragma unroll
        for (int j = 0; j < 4; j++) acc[i][j] = (f32x4){0.f, 0.f, 0.f, 0.f};

    for (int kt = 0; kt < EMB; kt += 32) {
        bf16x8 av0 = ld8_cvt(Aop  + (size_t)(m0 + ar0) * EMB + kt + ac0);
        bf16x8 av1 = ld8_cvt(Aop  + (size_t)(m0 + ar1) * EMB + kt + ac0);
        bf16x8 bv0 = ld8_cvt(w_in + (size_t)(n0g + ar0) * EMB + kt + ac0);
        bf16x8 bv1 = ld8_cvt(w_in + (size_t)(n0g + ar1) * EMB + kt + ac0);
        __syncthreads();
        *reinterpret_cast<bf16x8*>(lds_a + ar0 * 32 + ac0) = av0;
        *reinterpret_cast<bf16x8*>(lds_a + ar1 * 32 + ac0) = av1;
        *reinterpret_cast<bf16x8*>(lds_b + ar0 * 32 + ac0) = bv0;
        *reinterpret_cast<bf16x8*>(lds_b + ar1 * 32 + ac0) = bv1;
        __syncthreads();

        bf16x8 af[4], bfv[4];
        const int ka = quad * 8;
#pragma unroll
        for (int sm = 0; sm < 4; sm++)
            af[sm] = *reinterpret_cast<const bf16x8*>(lds_a + (wm + sm * 16 + lx) * 32 + ka);
#pragma unroll
        for (int sn = 0; sn < 4; sn++)
            bfv[sn] = *reinterpret_cast<const bf16x8*>(lds_b + (wn + sn * 16 + lx) * 32 + ka);
#pragma unroll
        for (int sm = 0; sm < 4; sm++)
#pragma unroll
            for (int sn = 0; sn < 4; sn++)
                acc[sm][sn] = mfma16(af[sm], bfv[sn], acc[sm][sn]);
    }

    const float scale = (chunk == 0) ? 0.125f : 1.0f;  // fold 1/sqrt(64) into Q
#pragma unroll
    for (int sn = 0; sn < 4; sn++) {
        const int n_g = n0g + wn + sn * 16 + lx;
        const float bias = b_in[n_g];
        const int nc = n_g & (EMB - 1);
        const int h  = nc >> 6;
        const int dd = nc & 63;
#pragma unroll
        for (int sm = 0; sm < 4; sm++) {
#pragma unroll
            for (int r = 0; r < 4; r++) {
                const int m_g = m0 + wm + sm * 16 + quad * 4 + r;  // row = l*B + b
                const int t = m_g >> 1;
                const int b = m_g & 1;
                const int bhidx = b * NH + h;
                const float v = (acc[sm][sn][r] + bias) * scale;
                if (chunk == 2) {
                    Vt[((size_t)bhidx * HD + dd) * S_SEQ + t] = __float2bfloat16(v);
                } else {
                    bf16* dst = (chunk == 0) ? Qh : Kh;
                    dst[((size_t)bhidx * S_SEQ + t) * HD + dd] = __float2bfloat16(v);
                }
            }
        }
    }
}

// ---------------------------------------------------------------------------
// Flash attention: one block = one (bh, 64-row Q tile); 4 waves x 16 rows.
// S iterated in 64-col tiles; online softmax; P round-trips LDS (C-layout ->
// A-layout); V arrives pre-transposed [bh][d][s] so all LDS traffic is b128.
// ctx written as [l*B+b][h*64+d] (GEMM-ready row-major).
// ---------------------------------------------------------------------------
#define KST 72  // padded LDS stride (72 % 8 == 0 keeps 16B alignment)

__global__ __launch_bounds__(256) void attn_kernel(
    const bf16* __restrict__ Qh, const bf16* __restrict__ Kh,
    const bf16* __restrict__ Vt, bf16* __restrict__ ctx)
{
    __shared__ alignas(16) bf16 k_lds[64 * KST];
    __shared__ alignas(16) bf16 v_lds[64 * KST];
    __shared__ alignas(16) bf16 p_lds[4][16 * KST];

    const int tid  = threadIdx.x;
    const int lane = tid & 63;
    const int wv   = tid >> 6;
    const int quad = lane >> 4;
    const int lx   = lane & 15;

    const int bh = blockIdx.y;
    const int l0 = blockIdx.x * 64;

    const bf16* Qbase = Qh + ((size_t)bh * L_SEQ + l0) * HD;
    const bf16* Kbase = Kh + (size_t)bh * S_SEQ * HD;
    const bf16* Vbase = Vt + (size_t)bh * HD * S_SEQ;

    // Q fragments live in registers for the whole kernel (already 1/8-scaled)
    const bf16* qrow = Qbase + (wv * 16 + lx) * HD + quad * 8;
    const bf16x8 qf0 = *reinterpret_cast<const bf16x8*>(qrow);
    const bf16x8 qf1 = *reinterpret_cast<const bf16x8*>(qrow + 32);

    float m_run[4], l_run[4];
    f32x4 accv[4];  // [sn] over 4 d-subtiles; regs = 4 rows
#pragma unroll
    for (int r = 0; r < 4; r++) {
        m_run[r] = -1e30f; l_run[r] = 0.f;
        accv[r] = (f32x4){0.f, 0.f, 0.f, 0.f};
    }

    // staging: 64x64 tile = 512 8-elem units; 2 per thread
    const int r0 = tid >> 3;
    const int c0 = (tid & 7) * 8;
    const int r1 = r0 + 32;

    for (int s0 = 0; s0 < S_SEQ; s0 += 64) {
        uint4 kv0 = *reinterpret_cast<const uint4*>(Kbase + (size_t)(s0 + r0) * HD + c0);
        uint4 kv1 = *reinterpret_cast<const uint4*>(Kbase + (size_t)(s0 + r1) * HD + c0);
        uint4 vv0 = *reinterpret_cast<const uint4*>(Vbase + (size_t)r0 * S_SEQ + s0 + c0);
        uint4 vv1 = *reinterpret_cast<const uint4*>(Vbase + (size_t)r1 * S_SEQ + s0 + c0);
        __syncthreads();
        *reinterpret_cast<uint4*>(k_lds + r0 * KST + c0) = kv0;
        *reinterpret_cast<uint4*>(k_lds + r1 * KST + c0) = kv1;
        *reinterpret_cast<uint4*>(v_lds + r0 * KST + c0) = vv0;
        *reinterpret_cast<uint4*>(v_lds + r1 * KST + c0) = vv1;
        __syncthreads();

        // scores: 16x64 per wave
        f32x4 sc[4];
#pragma unroll
        for (int sn = 0; sn < 4; sn++) {
            const bf16* krow = k_lds + (sn * 16 + lx) * KST + quad * 8;
            bf16x8 kf0 = *reinterpret_cast<const bf16x8*>(krow);
            bf16x8 kf1 = *reinterpret_cast<const bf16x8*>(krow + 32);
            f32x4 c = (f32x4){0.f, 0.f, 0.f, 0.f};
            c = mfma16(qf0, kf0, c);
            c = mfma16(qf1, kf1, c);
            sc[sn] = c;
        }

        // online softmax: rows are quad*4+r, cols spread over 16-lane groups
        float mx[4];
#pragma unroll
        for (int r = 0; r < 4; r++) {
            mx[r] = fmaxf(fmaxf(sc[0][r], sc[1][r]), fmaxf(sc[2][r], sc[3][r]));
            mx[r] = fmaxf(mx[r], __shfl_xor(mx[r], 1));
            mx[r] = fmaxf(mx[r], __shfl_xor(mx[r], 2));
            mx[r] = fmaxf(mx[r], __shfl_xor(mx[r], 4));
            mx[r] = fmaxf(mx[r], __shfl_xor(mx[r], 8));
        }
        float alpha[4], rs[4];
#pragma unroll
        for (int r = 0; r < 4; r++) {
            const float m_new = fmaxf(m_run[r], mx[r]);
            alpha[r] = __expf(m_run[r] - m_new);
            m_run[r] = m_new;
            rs[r] = 0.f;
        }
#pragma unroll
        for (int sn = 0; sn < 4; sn++)
#pragma unroll
            for (int r = 0; r < 4; r++) {
                const float p = __expf(sc[sn][r] - m_run[r]);
                sc[sn][r] = p;
                rs[r] += p;
            }
#pragma unroll
        for (int r = 0; r < 4; r++) {
            rs[r] += __shfl_xor(rs[r], 1);
            rs[r] += __shfl_xor(rs[r], 2);
            rs[r] += __shfl_xor(rs[r], 4);
            rs[r] += __shfl_xor(rs[r], 8);
            l_run[r] = l_run[r] * alpha[r] + rs[r];
        }
#pragma unroll
        for (int sn = 0; sn < 4; sn++)
#pragma unroll
            for (int r = 0; r < 4; r++)
                accv[sn][r] *= alpha[r];

        // P: C-layout -> LDS -> A-layout (per-wave private region)
#pragma unroll
        for (int sn = 0; sn < 4; sn++)
#pragma unroll
            for (int r = 0; r < 4; r++)
                p_lds[wv][(quad * 4 + r) * KST + sn * 16 + lx] = __float2bfloat16(sc[sn][r]);
        __syncthreads();

        const bf16* prow = p_lds[wv] + lx * KST + quad * 8;
        bf16x8 pf0 = *reinterpret_cast<const bf16x8*>(prow);
        bf16x8 pf1 = *reinterpret_cast<const bf16x8*>(prow + 32);
#pragma unroll
        for (int sn = 0; sn < 4; sn++) {
            const bf16* vrow = v_lds + (sn * 16 + lx) * KST + quad * 8;
            bf16x8 vf0 = *reinterpret_cast<const bf16x8*>(vrow);
            bf16x8 vf1 = *reinterpret_cast<const bf16x8*>(vrow + 32);
            accv[sn] = mfma16(pf0, vf0, accv[sn]);
            accv[sn] = mfma16(pf1, vf1, accv[sn]);
        }
    }

    const int b = bh >> 4;
    const int h = bh & 15;
#pragma unroll
    for (int sn = 0; sn < 4; sn++) {
#pragma unroll
        for (int r = 0; r < 4; r++) {
            const int l  = l0 + wv * 16 + quad * 4 + r;
            const int dd = sn * 16 + lx;
            const float v = accv[sn][r] / l_run[r];
            ctx[(size_t)(l * BATCH + b) * EMB + h * HD + dd] = __float2bfloat16(v);
        }
    }
}

// ---------------------------------------------------------------------------
// Output projection: out[m, n] = ctx[m,:] . w_out[n,:] + b_out[n]
// A = ctx (bf16, ws), B = w_out (fp32, converted in staging). Output FP32.
// M=4096, N=1024, K=1024. Same tile structure as qkv_gemm.
// ---------------------------------------------------------------------------
__global__ __launch_bounds__(256) void out_gemm(
    const bf16* __restrict__ ctx, const float* __restrict__ w_out,
    const float* __restrict__ b_out, float* __restrict__ out)
{
    __shared__ alignas(16) bf16 lds_a[128 * 32];
    __shared__ alignas(16) bf16 lds_b[128 * 32];

    const int tid  = threadIdx.x;
    const int lane = tid & 63;
    const int wv   = tid >> 6;
    const int quad = lane >> 4;
    const int lx   = lane & 15;

    const int m0 = blockIdx.x * 128;
    const int n0 = blockIdx.y * 128;

    const int wm = (wv >> 1) * 64;
    const int wn = (wv & 1) * 64;

    const int ar0 = tid >> 2;
    const int ac0 = (tid & 3) * 8;
    const int ar1 = ar0 + 64;

    f32x4 acc[4][4];
#pragma unroll
    for (int i = 0; i < 4; i++)
#pragma unroll
        for (int j = 0; j < 4; j++) acc[i][j] = (f32x4){0.f, 0.f, 0.f, 0.f};

    for (int kt = 0; kt < EMB; kt += 32) {
        uint4   av0 = *reinterpret_cast<const uint4*>(ctx + (size_t)(m0 + ar0) * EMB + kt + ac0);
        uint4   av1 = *reinterpret_cast<const uint4*>(ctx + (size_t)(m0 + ar1) * EMB + kt + ac0);
        bf16x8  bv0 = ld8_cvt(w_out + (size_t)(n0 + ar0) * EMB + kt + ac0);
        bf16x8  bv1 = ld8_cvt(w_out + (size_t)(n0 + ar1) * EMB + kt + ac0);
        __syncthreads();
        *reinterpret_cast<uint4*>(lds_a + ar0 * 32 + ac0) = av0;
        *reinterpret_cast<uint4*>(lds_a + ar1 * 32 + ac0) = av1;
        *reinterpret_cast<bf16x8*>(lds_b + ar0 * 32 + ac0) = bv0;
        *reinterpret_cast<bf16x8*>(lds_b + ar1 * 32 + ac0) = bv1;
        __syncthreads();

        bf16x8 af[4], bfv[4];
        const int ka = quad * 8;
#pragma unroll
        for (int sm = 0; sm < 4; sm++)
            af[sm] = *reinterpret_cast<const bf16x8*>(lds_a + (wm + sm * 16 + lx) * 32 + ka);
#pragma unroll
        for (int sn = 0; sn < 4; sn++)
            bfv[sn] = *reinterpret_cast<const bf16x8*>(lds_b + (wn + sn * 16 + lx) * 32 + ka);
#pragma unroll
        for (int sm = 0; sm < 4; sm++)
#pragma unroll
            for (int sn = 0; sn < 4; sn++)
                acc[sm][sn] = mfma16(af[sm], bfv[sn], acc[sm][sn]);
    }

#pragma unroll
    for (int sn = 0; sn < 4; sn++) {
        const int n_g = n0 + wn + sn * 16 + lx;
        const float bias = b_out[n_g];
#pragma unroll
        for (int sm = 0; sm < 4; sm++) {
#pragma unroll
            for (int r = 0; r < 4; r++) {
                const int m_g = m0 + wm + sm * 16 + quad * 4 + r;
                out[(size_t)m_g * EMB + n_g] = acc[sm][sn][r] + bias;
            }
        }
    }
}

extern "C" void kernel_launch(void* const* d_in, const int* in_sizes, int n_in,
                              void* d_out, int out_size, void* d_ws, size_t ws_size,
                              hipStream_t stream)
{
    const float* query = (const float*)d_in[0];
    const float* key_  = (const float*)d_in[1];
    const float* value = (const float*)d_in[2];
    const float* w_in  = (const float*)d_in[3];
    const float* b_in  = (const float*)d_in[4];
    const float* w_out = (const float*)d_in[5];
    const float* b_out = (const float*)d_in[6];
    float* out = (float*)d_out;

    const size_t seg = (size_t)MROWS * EMB;  // 4,194,304 elems = 8 MiB each
    bf16* Qh  = (bf16*)d_ws;                 // [bh][l][d], pre-scaled by 1/8
    bf16* Kh  = Qh + seg;                    // [bh][s][d]
    bf16* Vt  = Kh + seg;                    // [bh][d][s]  (transposed)
    bf16* ctx = Vt + seg;                    // [l*B+b][h*64+d]

    qkv_gemm<<<dim3(32, 24), 256, 0, stream>>>(query, key_, value, w_in, b_in, Qh, Kh, Vt);
    attn_kernel<<<dim3(32, 32), 256, 0, stream>>>(Qh, Kh, Vt, ctx);
    out_gemm<<<dim3(32, 8), 256, 0, stream>>>(ctx, w_out, b_out, out);
}

// Round 4
// 261.269 us; speedup vs baseline: 1.2016x; 1.2016x over previous
//
#include <hip/hip_runtime.h>
#include <hip/hip_bf16.h>
#include <stdint.h>

#define L_SEQ 2048
#define S_SEQ 2048
#define BATCH 2
#define EMB 1024
#define NH 16
#define HD 64
#define MROWS 4096  // L*B == S*B

typedef __bf16 bf16x8 __attribute__((ext_vector_type(8)));
typedef float f32x4 __attribute__((ext_vector_type(4)));
typedef __hip_bfloat16 bf16;

__device__ __forceinline__ f32x4 mfma16(bf16x8 a, bf16x8 b, f32x4 c) {
    return __builtin_amdgcn_mfma_f32_16x16x32_bf16(a, b, c, 0, 0, 0);
}

// async global->LDS, 16B per lane. LDS dest = wave-uniform base + lane*16.
__device__ __forceinline__ void gll16(const bf16* g, bf16* l) {
    __builtin_amdgcn_global_load_lds(
        (const __attribute__((address_space(1))) void*)g,
        (__attribute__((address_space(3))) void*)l, 16, 0, 0);
}

// load 8 consecutive fp32, round to bf16, pack into one 16B fragment
__device__ __forceinline__ bf16x8 ld8_cvt(const float* p) {
    const float4 a = *reinterpret_cast<const float4*>(p);
    const float4 b = *reinterpret_cast<const float4*>(p + 4);
    union { bf16x8 v; bf16 h[8]; } u;
    u.h[0] = __float2bfloat16(a.x); u.h[1] = __float2bfloat16(a.y);
    u.h[2] = __float2bfloat16(a.z); u.h[3] = __float2bfloat16(a.w);
    u.h[4] = __float2bfloat16(b.x); u.h[5] = __float2bfloat16(b.y);
    u.h[6] = __float2bfloat16(b.z); u.h[7] = __float2bfloat16(b.w);
    return u.v;
}

__device__ __forceinline__ uint32_t packbf2(float a, float b) {
    union { bf16 h[2]; uint32_t u; } t;
    t.h[0] = __float2bfloat16(a); t.h[1] = __float2bfloat16(b);
    return t.u;
}

// ---------------------------------------------------------------------------
// fp32 -> bf16 copies of the two weight matrices (once; GEMMs then use GLL).
// n_total = 3*EMB*EMB (w_in) + EMB*EMB (w_out) = 4,194,304; grid 2048 x 256 x 8.
// ---------------------------------------------------------------------------
__global__ __launch_bounds__(256) void cvt_kernel(
    const float* __restrict__ w_in, const float* __restrict__ w_out,
    bf16* __restrict__ wib, bf16* __restrict__ wob)
{
    const size_t i = ((size_t)blockIdx.x * 256 + threadIdx.x) * 8;
    const size_t n1 = (size_t)3 * EMB * EMB;
    const float* src; bf16* dst; size_t j;
    if (i < n1) { src = w_in; dst = wib; j = i; }
    else        { src = w_out; dst = wob; j = i - n1; }
    *reinterpret_cast<bf16x8*>(dst + j) = ld8_cvt(src + j);
}

// ---------------------------------------------------------------------------
// Fused QKV projection. A = X (fp32, reg-staged w/ cvt), B = wib (bf16, GLL).
// Epilogue: Qh[bh][l][d] (x0.125), Kh[bh][s][d], Vh[bh][s][d] (all coalesced).
// 128x128 tile, BK=32, 256 threads.
// ---------------------------------------------------------------------------
__global__ __launch_bounds__(256) void qkv_gemm(
    const float* __restrict__ q_in, const float* __restrict__ k_in,
    const float* __restrict__ v_in, const bf16* __restrict__ wib,
    const float* __restrict__ b_in,
    bf16* __restrict__ Qh, bf16* __restrict__ Kh, bf16* __restrict__ Vh)
{
    __shared__ alignas(16) bf16 lds_a[128 * 32];
    __shared__ alignas(16) bf16 lds_b[128 * 32];

    const int tid  = threadIdx.x;
    const int lane = tid & 63;
    const int wv   = tid >> 6;
    const int quad = lane >> 4;
    const int lx   = lane & 15;

    const int m0  = blockIdx.x * 128;
    const int n0g = blockIdx.y * 128;
    const int chunk = n0g >> 10;              // 0=Q, 1=K, 2=V
    const float* Aop = (chunk == 0) ? q_in : (chunk == 1) ? k_in : v_in;

    const int wm = (wv >> 1) * 64;
    const int wn = (wv & 1) * 64;

    const int ar0 = tid >> 2;
    const int ac0 = (tid & 3) * 8;
    const int ar1 = ar0 + 64;

    // GLL mapping for B: wave wv, issue i covers rows 16*wv+64*i + (lane>>2)
    const int gr = 16 * wv + (lane >> 2);
    const int gc = (lane & 3) * 8;
    const bf16* gB = wib + (size_t)(n0g + gr) * EMB + gc;
    bf16* lB = lds_b + wv * 512;              // elems; +2048 for issue 1

    f32x4 acc[4][4];
#pragma unroll
    for (int i = 0; i < 4; i++)
#pragma unroll
        for (int j = 0; j < 4; j++) acc[i][j] = (f32x4){0.f, 0.f, 0.f, 0.f};

    for (int kt = 0; kt < EMB; kt += 32) {
        bf16x8 av0 = ld8_cvt(Aop + (size_t)(m0 + ar0) * EMB + kt + ac0);
        bf16x8 av1 = ld8_cvt(Aop + (size_t)(m0 + ar1) * EMB + kt + ac0);
        __syncthreads();
        gll16(gB + kt, lB);
        gll16(gB + 64 * EMB + kt, lB + 2048);
        *reinterpret_cast<bf16x8*>(lds_a + ar0 * 32 + ac0) = av0;
        *reinterpret_cast<bf16x8*>(lds_a + ar1 * 32 + ac0) = av1;
        __syncthreads();

        bf16x8 af[4], bfv[4];
        const int ka = quad * 8;
#pragma unroll
        for (int sm = 0; sm < 4; sm++)
            af[sm] = *reinterpret_cast<const bf16x8*>(lds_a + (wm + sm * 16 + lx) * 32 + ka);
#pragma unroll
        for (int sn = 0; sn < 4; sn++)
            bfv[sn] = *reinterpret_cast<const bf16x8*>(lds_b + (wn + sn * 16 + lx) * 32 + ka);
#pragma unroll
        for (int sm = 0; sm < 4; sm++)
#pragma unroll
            for (int sn = 0; sn < 4; sn++)
                acc[sm][sn] = mfma16(af[sm], bfv[sn], acc[sm][sn]);
    }

    const float scale = (chunk == 0) ? 0.125f : 1.0f;
    bf16* dst = (chunk == 0) ? Qh : (chunk == 1) ? Kh : Vh;
#pragma unroll
    for (int sn = 0; sn < 4; sn++) {
        const int n_g = n0g + wn + sn * 16 + lx;
        const float bias = b_in[n_g];
        const int nc = n_g & (EMB - 1);
        const int h  = nc >> 6;
        const int dd = nc & 63;
#pragma unroll
        for (int sm = 0; sm < 4; sm++) {
#pragma unroll
            for (int r = 0; r < 4; r++) {
                const int m_g = m0 + wm + sm * 16 + quad * 4 + r;  // row = l*B + b
                const int t = m_g >> 1;
                const int b = m_g & 1;
                const int bhidx = b * NH + h;
                const float v = (acc[sm][sn][r] + bias) * scale;
                dst[((size_t)bhidx * S_SEQ + t) * HD + dd] = __float2bfloat16(v);
            }
        }
    }
}

// ---------------------------------------------------------------------------
// Vh [bh][s][d] -> Vt [bh][d][s].  64x64 tiles via LDS. grid (32 stiles, 32 bh)
// ---------------------------------------------------------------------------
#define TST 72
__global__ __launch_bounds__(256) void transpose_v(
    const bf16* __restrict__ Vh, bf16* __restrict__ Vt)
{
    __shared__ alignas(16) bf16 t[64 * TST];
    const int tid = threadIdx.x;
    const int bh  = blockIdx.y;
    const int s0  = blockIdx.x * 64;
    const int r0  = tid >> 3;          // 0..31
    const int c0  = (tid & 7) * 8;

    const bf16* src = Vh + (size_t)bh * S_SEQ * HD;
    uint4 a = *reinterpret_cast<const uint4*>(src + (size_t)(s0 + r0) * HD + c0);
    uint4 b = *reinterpret_cast<const uint4*>(src + (size_t)(s0 + r0 + 32) * HD + c0);
    *reinterpret_cast<uint4*>(t + r0 * TST + c0) = a;
    *reinterpret_cast<uint4*>(t + (r0 + 32) * TST + c0) = b;
    __syncthreads();

    const int sc = (tid & 7) * 8;
    bf16* dst = Vt + (size_t)bh * HD * S_SEQ;
#pragma unroll
    for (int half = 0; half < 2; half++) {
        const int d = (tid >> 3) + half * 32;
        union { bf16 h[8]; uint4 u; } o;
#pragma unroll
        for (int j = 0; j < 8; j++) o.h[j] = t[(sc + j) * TST + d];
        *reinterpret_cast<uint4*>(dst + (size_t)d * S_SEQ + s0 + sc) = o.u;
    }
}

// ---------------------------------------------------------------------------
// Flash attention, S^T orientation. Block = (bh, 128 q rows), 8 waves x 16 q.
// S-tile 128. QK computed as T[s][q] (lane holds q=lx -> per-lane softmax
// scalars). P stored to per-wave LDS via packed b64 (no barrier), read back
// as A-frags. K/V/P LDS XOR-swizzled (chunk ^ row&7) -> bank-balanced.
// ---------------------------------------------------------------------------
__global__ __launch_bounds__(512, 4) void attn_kernel(
    const bf16* __restrict__ Qh, const bf16* __restrict__ Kh,
    const bf16* __restrict__ Vt, bf16* __restrict__ ctx)
{
    __shared__ alignas(16) bf16 k_lds[128 * 64];     // [s][d] swizzled
    __shared__ alignas(16) bf16 v_lds[64 * 128];     // [d][s] swizzled
    __shared__ alignas(16) bf16 p_lds[8][16 * 128];  // per-wave [q][s] swizzled

    const int tid  = threadIdx.x;
    const int lane = tid & 63;
    const int wv   = tid >> 6;      // 0..7
    const int quad = lane >> 4;
    const int lx   = lane & 15;
    const int lx7  = lane & 7;

    const int bh = blockIdx.y;
    const int l0 = blockIdx.x * 128;
    const int q0 = wv * 16;

    const bf16* Kbase = Kh + (size_t)bh * S_SEQ * HD;
    const bf16* Vbase = Vt + (size_t)bh * HD * S_SEQ;

    // Q as B-operand: lane holds Q[q0+lx][d = quad*8+j] (pre-scaled by 1/8)
    const bf16* qrow = Qh + ((size_t)bh * L_SEQ + l0 + q0 + lx) * HD + quad * 8;
    const bf16x8 qf0 = *reinterpret_cast<const bf16x8*>(qrow);
    const bf16x8 qf1 = *reinterpret_cast<const bf16x8*>(qrow + 32);

    float m_run = -1e30f, l_run = 0.f;
    f32x4 accv[4];
#pragma unroll
    for (int sn = 0; sn < 4; sn++) accv[sn] = (f32x4){0.f, 0.f, 0.f, 0.f};

    // staging assignments (512 threads)
    const int kr0 = tid >> 3;             // 0..63 (+64)
    const int kc  = (tid & 7) * 8;
    const int vd0 = tid >> 4;             // 0..31 (+32)
    const int vs  = (tid & 15) * 8;

    bf16* p_w = &p_lds[wv][0];

    for (int s0 = 0; s0 < S_SEQ; s0 += 128) {
        uint4 ka = *reinterpret_cast<const uint4*>(Kbase + (size_t)(s0 + kr0) * HD + kc);
        uint4 kb = *reinterpret_cast<const uint4*>(Kbase + (size_t)(s0 + kr0 + 64) * HD + kc);
        uint4 va = *reinterpret_cast<const uint4*>(Vbase + (size_t)vd0 * S_SEQ + s0 + vs);
        uint4 vb = *reinterpret_cast<const uint4*>(Vbase + (size_t)(vd0 + 32) * S_SEQ + s0 + vs);
        __syncthreads();
        {
            const int ksw = (((kc >> 3) ^ (kr0 & 7)) << 3);   // (kr0+64)&7 == kr0&7
            *reinterpret_cast<uint4*>(k_lds + kr0 * 64 + ksw) = ka;
            *reinterpret_cast<uint4*>(k_lds + (kr0 + 64) * 64 + ksw) = kb;
            const int vsw = (((vs >> 3) ^ (vd0 & 7)) << 3);   // (vd0+32)&7 == vd0&7
            *reinterpret_cast<uint4*>(v_lds + vd0 * 128 + vsw) = va;
            *reinterpret_cast<uint4*>(v_lds + (vd0 + 32) * 128 + vsw) = vb;
        }
        __syncthreads();

        // QK^T transposed: T[s = c*16 + quad*4 + r][q = q0 + lx]
        f32x4 sc[8];
#pragma unroll
        for (int c = 0; c < 8; c++) {
            const bf16* kr = k_lds + (c * 16 + lx) * 64;
            bf16x8 kf0 = *reinterpret_cast<const bf16x8*>(kr + ((quad ^ lx7) << 3));
            bf16x8 kf1 = *reinterpret_cast<const bf16x8*>(kr + (((quad + 4) ^ lx7) << 3));
            f32x4 tt = (f32x4){0.f, 0.f, 0.f, 0.f};
            tt = mfma16(kf0, qf0, tt);
            tt = mfma16(kf1, qf1, tt);
            sc[c] = tt;
        }

        // online softmax over s, per-lane row q=lx
        float mloc = sc[0][0];
#pragma unroll
        for (int c = 0; c < 8; c++)
#pragma unroll
            for (int r = 0; r < 4; r++) mloc = fmaxf(mloc, sc[c][r]);
        mloc = fmaxf(mloc, __shfl_xor(mloc, 16));
        mloc = fmaxf(mloc, __shfl_xor(mloc, 32));
        const float mnew = fmaxf(m_run, mloc);
        const float al = __expf(m_run - mnew);
        m_run = mnew;
        float rsum = 0.f;
#pragma unroll
        for (int c = 0; c < 8; c++)
#pragma unroll
            for (int r = 0; r < 4; r++) {
                const float p = __expf(sc[c][r] - mnew);
                sc[c][r] = p;
                rsum += p;
            }
        rsum += __shfl_xor(rsum, 16);
        rsum += __shfl_xor(rsum, 32);
        l_run = l_run * al + rsum;

        // rescale accumulator rows (O rows are q = quad*4+r)
#pragma unroll
        for (int r = 0; r < 4; r++) {
            const float ar = __shfl(al, quad * 20 + r);  // lane quad*16 + quad*4+r
#pragma unroll
            for (int sn = 0; sn < 4; sn++) accv[sn][r] *= ar;
        }

        // P store: per lane 4 contiguous s per chunk c -> packed b64
#pragma unroll
        for (int c = 0; c < 8; c++) {
            uint2 pk;
            pk.x = packbf2(sc[c][0], sc[c][1]);
            pk.y = packbf2(sc[c][2], sc[c][3]);
            const int off = lx * 128 + ((((c * 2 + (quad >> 1)) ^ lx7)) << 3) + ((quad & 1) << 2);
            *reinterpret_cast<uint2*>(p_w + off) = pk;
        }

        // PV: O[q][d] += P[q][s] V[s][d]   (per-wave P, no barrier needed)
#pragma unroll
        for (int sk = 0; sk < 4; sk++) {
            bf16x8 pf = *reinterpret_cast<const bf16x8*>(
                p_w + lx * 128 + ((((sk * 4 + quad) ^ lx7)) << 3));
#pragma unroll
            for (int sn = 0; sn < 4; sn++) {
                const bf16* vr = v_lds + (sn * 16 + lx) * 128 + ((((sk * 4 + quad) ^ lx7)) << 3);
                accv[sn] = mfma16(pf, *reinterpret_cast<const bf16x8*>(vr), accv[sn]);
            }
        }
    }

    const int b = bh >> 4;
    const int h = bh & 15;
#pragma unroll
    for (int r = 0; r < 4; r++) {
        const float lr = __shfl(l_run, quad * 20 + r);
        const float inv = 1.f / lr;
        const int l = l0 + q0 + quad * 4 + r;
#pragma unroll
        for (int sn = 0; sn < 4; sn++) {
            const int dd = sn * 16 + lx;
            ctx[(size_t)(l * BATCH + b) * EMB + h * HD + dd] =
                __float2bfloat16(accv[sn][r] * inv);
        }
    }
}

// ---------------------------------------------------------------------------
// Output projection: both tiles via GLL (A = ctx bf16, B = wob bf16). fp32 out.
// ---------------------------------------------------------------------------
__global__ __launch_bounds__(256) void out_gemm(
    const bf16* __restrict__ ctx, const bf16* __restrict__ wob,
    const float* __restrict__ b_out, float* __restrict__ out)
{
    __shared__ alignas(16) bf16 lds_a[128 * 32];
    __shared__ alignas(16) bf16 lds_b[128 * 32];

    const int tid  = threadIdx.x;
    const int lane = tid & 63;
    const int wv   = tid >> 6;
    const int quad = lane >> 4;
    const int lx   = lane & 15;

    const int m0 = blockIdx.x * 128;
    const int n0 = blockIdx.y * 128;

    const int wm = (wv >> 1) * 64;
    const int wn = (wv & 1) * 64;

    const int gr = 16 * wv + (lane >> 2);
    const int gc = (lane & 3) * 8;
    const bf16* gA = ctx + (size_t)(m0 + gr) * EMB + gc;
    const bf16* gB = wob + (size_t)(n0 + gr) * EMB + gc;
    bf16* lA = lds_a + wv * 512;
    bf16* lB = lds_b + wv * 512;

    f32x4 acc[4][4];
#pragma unroll
    for (int i = 0; i < 4; i++)
#pragma unroll
        for (int j = 0; j < 4; j++) acc[i][j] = (f32x4){0.f, 0.f, 0.f, 0.f};

    for (int kt = 0; kt < EMB; kt += 32) {
        __syncthreads();
        gll16(gA + kt, lA);
        gll16(gA + 64 * EMB + kt, lA + 2048);
        gll16(gB + kt, lB);
        gll16(gB + 64 * EMB + kt, lB + 2048);
        __syncthreads();

        bf16x8 af[4], bfv[4];
        const int ka = quad * 8;
#pragma unroll
        for (int sm = 0; sm < 4; sm++)
            af[sm] = *reinterpret_cast<const bf16x8*>(lds_a + (wm + sm * 16 + lx) * 32 + ka);
#pragma unroll
        for (int sn = 0; sn < 4; sn++)
            bfv[sn] = *reinterpret_cast<const bf16x8*>(lds_b + (wn + sn * 16 + lx) * 32 + ka);
#pragma unroll
        for (int sm = 0; sm < 4; sm++)
#pragma unroll
            for (int sn = 0; sn < 4; sn++)
                acc[sm][sn] = mfma16(af[sm], bfv[sn], acc[sm][sn]);
    }

#pragma unroll
    for (int sn = 0; sn < 4; sn++) {
        const int n_g = n0 + wn + sn * 16 + lx;
        const float bias = b_out[n_g];
#pragma unroll
        for (int sm = 0; sm < 4; sm++) {
#pragma unroll
            for (int r = 0; r < 4; r++) {
                const int m_g = m0 + wm + sm * 16 + quad * 4 + r;
                out[(size_t)m_g * EMB + n_g] = acc[sm][sn][r] + bias;
            }
        }
    }
}

extern "C" void kernel_launch(void* const* d_in, const int* in_sizes, int n_in,
                              void* d_out, int out_size, void* d_ws, size_t ws_size,
                              hipStream_t stream)
{
    const float* query = (const float*)d_in[0];
    const float* key_  = (const float*)d_in[1];
    const float* value = (const float*)d_in[2];
    const float* w_in  = (const float*)d_in[3];
    const float* b_in  = (const float*)d_in[4];
    const float* w_out = (const float*)d_in[5];
    const float* b_out = (const float*)d_in[6];
    float* out = (float*)d_out;

    const size_t seg = (size_t)MROWS * EMB;      // 4,194,304 elems (8 MiB bf16)
    bf16* wib = (bf16*)d_ws;                     // 3*EMB*EMB
    bf16* wob = wib + (size_t)3 * EMB * EMB;     // EMB*EMB
    bf16* Qh  = wob + (size_t)EMB * EMB;         // [bh][l][d], pre-scaled 1/8
    bf16* Kh  = Qh + seg;                        // [bh][s][d]
    bf16* Vh  = Kh + seg;                        // [bh][s][d]
    bf16* Vt  = Vh + seg;                        // [bh][d][s]
    bf16* ctx = Vh;                              // alias: Vh dead after transpose

    cvt_kernel<<<2048, 256, 0, stream>>>(w_in, w_out, wib, wob);
    qkv_gemm<<<dim3(32, 24), 256, 0, stream>>>(query, key_, value, wib, b_in, Qh, Kh, Vh);
    transpose_v<<<dim3(32, 32), 256, 0, stream>>>(Vh, Vt);
    attn_kernel<<<dim3(16, 32), 512, 0, stream>>>(Qh, Kh, Vt, ctx);
    out_gemm<<<dim3(32, 8), 256, 0, stream>>>(ctx, wob, b_out, out);
}

// Round 6
// 239.490 us; speedup vs baseline: 1.3109x; 1.0909x over previous
//
#include <hip/hip_runtime.h>
#include <hip/hip_bf16.h>
#include <stdint.h>

#define L_SEQ 2048
#define S_SEQ 2048
#define BATCH 2
#define EMB 1024
#define NH 16
#define HD 64
#define MROWS 4096  // L*B == S*B

typedef __bf16 bf16x8 __attribute__((ext_vector_type(8)));
typedef float f32x4 __attribute__((ext_vector_type(4)));
typedef __hip_bfloat16 bf16;

__device__ __forceinline__ f32x4 mfma16(bf16x8 a, bf16x8 b, f32x4 c) {
    return __builtin_amdgcn_mfma_f32_16x16x32_bf16(a, b, c, 0, 0, 0);
}

// async global->LDS, 16B per lane. LDS dest = wave-uniform base + lane*16.
__device__ __forceinline__ void gll16(const bf16* g, bf16* l) {
    __builtin_amdgcn_global_load_lds(
        (const __attribute__((address_space(1))) void*)g,
        (__attribute__((address_space(3))) void*)l, 16, 0, 0);
}

// load 8 consecutive fp32, round to bf16, pack into one 16B fragment
__device__ __forceinline__ bf16x8 ld8_cvt(const float* p) {
    const float4 a = *reinterpret_cast<const float4*>(p);
    const float4 b = *reinterpret_cast<const float4*>(p + 4);
    union { bf16x8 v; bf16 h[8]; } u;
    u.h[0] = __float2bfloat16(a.x); u.h[1] = __float2bfloat16(a.y);
    u.h[2] = __float2bfloat16(a.z); u.h[3] = __float2bfloat16(a.w);
    u.h[4] = __float2bfloat16(b.x); u.h[5] = __float2bfloat16(b.y);
    u.h[6] = __float2bfloat16(b.z); u.h[7] = __float2bfloat16(b.w);
    return u.v;
}

__device__ __forceinline__ uint32_t packbf2(float a, float b) {
    union { bf16 h[2]; uint32_t u; } t;
    t.h[0] = __float2bfloat16(a); t.h[1] = __float2bfloat16(b);
    return t.u;
}

// ---------------------------------------------------------------------------
// fp32 -> bf16 for w_in, w_out, q, k, v (one memory-bound pass; GEMMs use GLL).
// Regions: [w_in 3M | w_out 1M | q 4M | k 4M | v 4M] = 16,777,216 elems.
// grid 8192 x 256 x 8 elems.
// ---------------------------------------------------------------------------
__global__ __launch_bounds__(256) void cvt_kernel(
    const float* __restrict__ w_in, const float* __restrict__ w_out,
    const float* __restrict__ q_in, const float* __restrict__ k_in,
    const float* __restrict__ v_in,
    bf16* __restrict__ wib, bf16* __restrict__ wob,
    bf16* __restrict__ Xq, bf16* __restrict__ Xk, bf16* __restrict__ Xv)
{
    const size_t i = ((size_t)blockIdx.x * 256 + threadIdx.x) * 8;
    const size_t o1 = (size_t)3 * EMB * EMB;        //  3,145,728
    const size_t o2 = o1 + (size_t)EMB * EMB;       //  4,194,304
    const size_t o3 = o2 + (size_t)MROWS * EMB;     //  8,388,608
    const size_t o4 = o3 + (size_t)MROWS * EMB;     // 12,582,912
    const float* src; bf16* dst; size_t j;
    if      (i < o1) { src = w_in;  dst = wib; j = i; }
    else if (i < o2) { src = w_out; dst = wob; j = i - o1; }
    else if (i < o3) { src = q_in;  dst = Xq;  j = i - o2; }
    else if (i < o4) { src = k_in;  dst = Xk;  j = i - o3; }
    else             { src = v_in;  dst = Xv;  j = i - o4; }
    *reinterpret_cast<bf16x8*>(dst + j) = ld8_cvt(src + j);
}

// ---------------------------------------------------------------------------
// Fused QKV projection, pure m97 structure: GLL for A (Xq/Xk/Xv bf16) and
// B (wib bf16). Epilogue: Qh[bh][l][d] (x0.125), Kh[bh][s][d], Vh[bh][s][d].
// 128x128 tile, BK=32, 256 threads.
// ---------------------------------------------------------------------------
__global__ __launch_bounds__(256) void qkv_gemm(
    const bf16* __restrict__ Xq, const bf16* __restrict__ Xk,
    const bf16* __restrict__ Xv, const bf16* __restrict__ wib,
    const float* __restrict__ b_in,
    bf16* __restrict__ Qh, bf16* __restrict__ Kh, bf16* __restrict__ Vh)
{
    __shared__ alignas(16) bf16 lds_a[128 * 32];
    __shared__ alignas(16) bf16 lds_b[128 * 32];

    const int tid  = threadIdx.x;
    const int lane = tid & 63;
    const int wv   = tid >> 6;
    const int quad = lane >> 4;
    const int lx   = lane & 15;

    const int m0  = blockIdx.x * 128;
    const int n0g = blockIdx.y * 128;
    const int chunk = n0g >> 10;              // 0=Q, 1=K, 2=V
    const bf16* Aop = (chunk == 0) ? Xq : (chunk == 1) ? Xk : Xv;

    const int wm = (wv >> 1) * 64;
    const int wn = (wv & 1) * 64;

    // GLL mapping: wave wv, issue i covers rows 16*wv + 64*i + (lane>>2)
    const int gr = 16 * wv + (lane >> 2);
    const int gc = (lane & 3) * 8;
    const bf16* gA = Aop + (size_t)(m0 + gr) * EMB + gc;
    const bf16* gB = wib + (size_t)(n0g + gr) * EMB + gc;
    bf16* lA = lds_a + wv * 512;              // elems; +2048 for issue 1
    bf16* lB = lds_b + wv * 512;

    f32x4 acc[4][4];
#pragma unroll
    for (int i = 0; i < 4; i++)
#pragma unroll
        for (int j = 0; j < 4; j++) acc[i][j] = (f32x4){0.f, 0.f, 0.f, 0.f};

    for (int kt = 0; kt < EMB; kt += 32) {
        __syncthreads();
        gll16(gA + kt, lA);
        gll16(gA + 64 * EMB + kt, lA + 2048);
        gll16(gB + kt, lB);
        gll16(gB + 64 * EMB + kt, lB + 2048);
        __syncthreads();

        bf16x8 af[4], bfv[4];
        const int ka = quad * 8;
#pragma unroll
        for (int sm = 0; sm < 4; sm++)
            af[sm] = *reinterpret_cast<const bf16x8*>(lds_a + (wm + sm * 16 + lx) * 32 + ka);
#pragma unroll
        for (int sn = 0; sn < 4; sn++)
            bfv[sn] = *reinterpret_cast<const bf16x8*>(lds_b + (wn + sn * 16 + lx) * 32 + ka);
#pragma unroll
        for (int sm = 0; sm < 4; sm++)
#pragma unroll
            for (int sn = 0; sn < 4; sn++)
                acc[sm][sn] = mfma16(af[sm], bfv[sn], acc[sm][sn]);
    }

    const float scale = (chunk == 0) ? 0.125f : 1.0f;
    bf16* dst = (chunk == 0) ? Qh : (chunk == 1) ? Kh : Vh;
#pragma unroll
    for (int sn = 0; sn < 4; sn++) {
        const int n_g = n0g + wn + sn * 16 + lx;
        const float bias = b_in[n_g];
        const int nc = n_g & (EMB - 1);
        const int h  = nc >> 6;
        const int dd = nc & 63;
#pragma unroll
        for (int sm = 0; sm < 4; sm++) {
#pragma unroll
            for (int r = 0; r < 4; r++) {
                const int m_g = m0 + wm + sm * 16 + quad * 4 + r;  // row = l*B + b
                const int t = m_g >> 1;
                const int b = m_g & 1;
                const int bhidx = b * NH + h;
                const float v = (acc[sm][sn][r] + bias) * scale;
                dst[((size_t)bhidx * S_SEQ + t) * HD + dd] = __float2bfloat16(v);
            }
        }
    }
}

// ---------------------------------------------------------------------------
// Vh [bh][s][d] -> Vt [bh][d][s].  64x64 tiles via LDS. grid (32 stiles, 32 bh)
// ---------------------------------------------------------------------------
#define TST 72
__global__ __launch_bounds__(256) void transpose_v(
    const bf16* __restrict__ Vh, bf16* __restrict__ Vt)
{
    __shared__ alignas(16) bf16 t[64 * TST];
    const int tid = threadIdx.x;
    const int bh  = blockIdx.y;
    const int s0  = blockIdx.x * 64;
    const int r0  = tid >> 3;          // 0..31
    const int c0  = (tid & 7) * 8;

    const bf16* src = Vh + (size_t)bh * S_SEQ * HD;
    uint4 a = *reinterpret_cast<const uint4*>(src + (size_t)(s0 + r0) * HD + c0);
    uint4 b = *reinterpret_cast<const uint4*>(src + (size_t)(s0 + r0 + 32) * HD + c0);
    *reinterpret_cast<uint4*>(t + r0 * TST + c0) = a;
    *reinterpret_cast<uint4*>(t + (r0 + 32) * TST + c0) = b;
    __syncthreads();

    const int sc = (tid & 7) * 8;
    bf16* dst = Vt + (size_t)bh * HD * S_SEQ;
#pragma unroll
    for (int half = 0; half < 2; half++) {
        const int d = (tid >> 3) + half * 32;
        union { bf16 h[8]; uint4 u; } o;
#pragma unroll
        for (int j = 0; j < 8; j++) o.h[j] = t[(sc + j) * TST + d];
        *reinterpret_cast<uint4*>(dst + (size_t)d * S_SEQ + s0 + sc) = o.u;
    }
}

// ---------------------------------------------------------------------------
// Flash attention, S^T orientation. Block = (bh, 128 q rows), 8 waves x 16 q.
// S-tile 128. QK computed as T[s][q] (lane holds q=lx -> per-lane softmax
// scalars). P stored to per-wave LDS via packed b64 (no barrier), read back
// as A-frags. K/V/P LDS XOR-swizzled (chunk ^ row&7) -> bank-balanced.
// ---------------------------------------------------------------------------
__global__ __launch_bounds__(512, 4) void attn_kernel(
    const bf16* __restrict__ Qh, const bf16* __restrict__ Kh,
    const bf16* __restrict__ Vt, bf16* __restrict__ ctx)
{
    __shared__ alignas(16) bf16 k_lds[128 * 64];     // [s][d] swizzled
    __shared__ alignas(16) bf16 v_lds[64 * 128];     // [d][s] swizzled
    __shared__ alignas(16) bf16 p_lds[8][16 * 128];  // per-wave [q][s] swizzled

    const int tid  = threadIdx.x;
    const int lane = tid & 63;
    const int wv   = tid >> 6;      // 0..7
    const int quad = lane >> 4;
    const int lx   = lane & 15;
    const int lx7  = lane & 7;

    const int bh = blockIdx.y;
    const int l0 = blockIdx.x * 128;
    const int q0 = wv * 16;

    const bf16* Kbase = Kh + (size_t)bh * S_SEQ * HD;
    const bf16* Vbase = Vt + (size_t)bh * HD * S_SEQ;

    // Q as B-operand: lane holds Q[q0+lx][d = quad*8+j] (pre-scaled by 1/8)
    const bf16* qrow = Qh + ((size_t)bh * L_SEQ + l0 + q0 + lx) * HD + quad * 8;
    const bf16x8 qf0 = *reinterpret_cast<const bf16x8*>(qrow);
    const bf16x8 qf1 = *reinterpret_cast<const bf16x8*>(qrow + 32);

    float m_run = -1e30f, l_run = 0.f;
    f32x4 accv[4];
#pragma unroll
    for (int sn = 0; sn < 4; sn++) accv[sn] = (f32x4){0.f, 0.f, 0.f, 0.f};

    // staging assignments (512 threads)
    const int kr0 = tid >> 3;             // 0..63 (+64)
    const int kc  = (tid & 7) * 8;
    const int vd0 = tid >> 4;             // 0..31 (+32)
    const int vs  = (tid & 15) * 8;

    bf16* p_w = &p_lds[wv][0];

    for (int s0 = 0; s0 < S_SEQ; s0 += 128) {
        uint4 ka = *reinterpret_cast<const uint4*>(Kbase + (size_t)(s0 + kr0) * HD + kc);
        uint4 kb = *reinterpret_cast<const uint4*>(Kbase + (size_t)(s0 + kr0 + 64) * HD + kc);
        uint4 va = *reinterpret_cast<const uint4*>(Vbase + (size_t)vd0 * S_SEQ + s0 + vs);
        uint4 vb = *reinterpret_cast<const uint4*>(Vbase + (size_t)(vd0 + 32) * S_SEQ + s0 + vs);
        __syncthreads();
        {
            const int ksw = (((kc >> 3) ^ (kr0 & 7)) << 3);   // (kr0+64)&7 == kr0&7
            *reinterpret_cast<uint4*>(k_lds + kr0 * 64 + ksw) = ka;
            *reinterpret_cast<uint4*>(k_lds + (kr0 + 64) * 64 + ksw) = kb;
            const int vsw = (((vs >> 3) ^ (vd0 & 7)) << 3);   // (vd0+32)&7 == vd0&7
            *reinterpret_cast<uint4*>(v_lds + vd0 * 128 + vsw) = va;
            *reinterpret_cast<uint4*>(v_lds + (vd0 + 32) * 128 + vsw) = vb;
        }
        __syncthreads();

        // QK^T transposed: T[s = c*16 + quad*4 + r][q = q0 + lx]
        f32x4 sc[8];
#pragma unroll
        for (int c = 0; c < 8; c++) {
            const bf16* kr = k_lds + (c * 16 + lx) * 64;
            bf16x8 kf0 = *reinterpret_cast<const bf16x8*>(kr + ((quad ^ lx7) << 3));
            bf16x8 kf1 = *reinterpret_cast<const bf16x8*>(kr + (((quad + 4) ^ lx7) << 3));
            f32x4 tt = (f32x4){0.f, 0.f, 0.f, 0.f};
            tt = mfma16(kf0, qf0, tt);
            tt = mfma16(kf1, qf1, tt);
            sc[c] = tt;
        }

        // online softmax over s, per-lane row q=lx
        float mloc = sc[0][0];
#pragma unroll
        for (int c = 0; c < 8; c++)
#pragma unroll
            for (int r = 0; r < 4; r++) mloc = fmaxf(mloc, sc[c][r]);
        mloc = fmaxf(mloc, __shfl_xor(mloc, 16));
        mloc = fmaxf(mloc, __shfl_xor(mloc, 32));
        const float mnew = fmaxf(m_run, mloc);
        const float al = __expf(m_run - mnew);
        m_run = mnew;
        float rsum = 0.f;
#pragma unroll
        for (int c = 0; c < 8; c++)
#pragma unroll
            for (int r = 0; r < 4; r++) {
                const float p = __expf(sc[c][r] - mnew);
                sc[c][r] = p;
                rsum += p;
            }
        rsum += __shfl_xor(rsum, 16);
        rsum += __shfl_xor(rsum, 32);
        l_run = l_run * al + rsum;

        // rescale accumulator rows (O rows are q = quad*4+r)
#pragma unroll
        for (int r = 0; r < 4; r++) {
            const float ar = __shfl(al, quad * 20 + r);  // lane quad*16 + quad*4+r
#pragma unroll
            for (int sn = 0; sn < 4; sn++) accv[sn][r] *= ar;
        }

        // P store: per lane 4 contiguous s per chunk c -> packed b64
#pragma unroll
        for (int c = 0; c < 8; c++) {
            uint2 pk;
            pk.x = packbf2(sc[c][0], sc[c][1]);
            pk.y = packbf2(sc[c][2], sc[c][3]);
            const int off = lx * 128 + ((((c * 2 + (quad >> 1)) ^ lx7)) << 3) + ((quad & 1) << 2);
            *reinterpret_cast<uint2*>(p_w + off) = pk;
        }

        // PV: O[q][d] += P[q][s] V[s][d]   (per-wave P, no barrier needed)
#pragma unroll
        for (int sk = 0; sk < 4; sk++) {
            bf16x8 pf = *reinterpret_cast<const bf16x8*>(
                p_w + lx * 128 + ((((sk * 4 + quad) ^ lx7)) << 3));
#pragma unroll
            for (int sn = 0; sn < 4; sn++) {
                const bf16* vr = v_lds + (sn * 16 + lx) * 128 + ((((sk * 4 + quad) ^ lx7)) << 3);
                accv[sn] = mfma16(pf, *reinterpret_cast<const bf16x8*>(vr), accv[sn]);
            }
        }
    }

    const int b = bh >> 4;
    const int h = bh & 15;
#pragma unroll
    for (int r = 0; r < 4; r++) {
        const float lr = __shfl(l_run, quad * 20 + r);
        const float inv = 1.f / lr;
        const int l = l0 + q0 + quad * 4 + r;
#pragma unroll
        for (int sn = 0; sn < 4; sn++) {
            const int dd = sn * 16 + lx;
            ctx[(size_t)(l * BATCH + b) * EMB + h * HD + dd] =
                __float2bfloat16(accv[sn][r] * inv);
        }
    }
}

// ---------------------------------------------------------------------------
// Output projection: both tiles via GLL (A = ctx bf16, B = wob bf16). fp32 out.
// ---------------------------------------------------------------------------
__global__ __launch_bounds__(256) void out_gemm(
    const bf16* __restrict__ ctx, const bf16* __restrict__ wob,
    const float* __restrict__ b_out, float* __restrict__ out)
{
    __shared__ alignas(16) bf16 lds_a[128 * 32];
    __shared__ alignas(16) bf16 lds_b[128 * 32];

    const int tid  = threadIdx.x;
    const int lane = tid & 63;
    const int wv   = tid >> 6;
    const int quad = lane >> 4;
    const int lx   = lane & 15;

    const int m0 = blockIdx.x * 128;
    const int n0 = blockIdx.y * 128;

    const int wm = (wv >> 1) * 64;
    const int wn = (wv & 1) * 64;

    const int gr = 16 * wv + (lane >> 2);
    const int gc = (lane & 3) * 8;
    const bf16* gA = ctx + (size_t)(m0 + gr) * EMB + gc;
    const bf16* gB = wob + (size_t)(n0 + gr) * EMB + gc;
    bf16* lA = lds_a + wv * 512;
    bf16* lB = lds_b + wv * 512;

    f32x4 acc[4][4];
#pragma unroll
    for (int i = 0; i < 4; i++)
#pragma unroll
        for (int j = 0; j < 4; j++) acc[i][j] = (f32x4){0.f, 0.f, 0.f, 0.f};

    for (int kt = 0; kt < EMB; kt += 32) {
        __syncthreads();
        gll16(gA + kt, lA);
        gll16(gA + 64 * EMB + kt, lA + 2048);
        gll16(gB + kt, lB);
        gll16(gB + 64 * EMB + kt, lB + 2048);
        __syncthreads();

        bf16x8 af[4], bfv[4];
        const int ka = quad * 8;
#pragma unroll
        for (int sm = 0; sm < 4; sm++)
            af[sm] = *reinterpret_cast<const bf16x8*>(lds_a + (wm + sm * 16 + lx) * 32 + ka);
#pragma unroll
        for (int sn = 0; sn < 4; sn++)
            bfv[sn] = *reinterpret_cast<const bf16x8*>(lds_b + (wn + sn * 16 + lx) * 32 + ka);
#pragma unroll
        for (int sm = 0; sm < 4; sm++)
#pragma unroll
            for (int sn = 0; sn < 4; sn++)
                acc[sm][sn] = mfma16(af[sm], bfv[sn], acc[sm][sn]);
    }

#pragma unroll
    for (int sn = 0; sn < 4; sn++) {
        const int n_g = n0 + wn + sn * 16 + lx;
        const float bias = b_out[n_g];
#pragma unroll
        for (int sm = 0; sm < 4; sm++) {
#pragma unroll
            for (int r = 0; r < 4; r++) {
                const int m_g = m0 + wm + sm * 16 + quad * 4 + r;
                out[(size_t)m_g * EMB + n_g] = acc[sm][sn][r] + bias;
            }
        }
    }
}

extern "C" void kernel_launch(void* const* d_in, const int* in_sizes, int n_in,
                              void* d_out, int out_size, void* d_ws, size_t ws_size,
                              hipStream_t stream)
{
    const float* query = (const float*)d_in[0];
    const float* key_  = (const float*)d_in[1];
    const float* value = (const float*)d_in[2];
    const float* w_in  = (const float*)d_in[3];
    const float* b_in  = (const float*)d_in[4];
    const float* w_out = (const float*)d_in[5];
    const float* b_out = (const float*)d_in[6];
    float* out = (float*)d_out;

    const size_t seg = (size_t)MROWS * EMB;      // 4,194,304 elems (8 MiB bf16)
    bf16* wib = (bf16*)d_ws;                     // 3*EMB*EMB
    bf16* wob = wib + (size_t)3 * EMB * EMB;     // EMB*EMB
    bf16* Xq  = wob + (size_t)EMB * EMB;         // [m][k] bf16 inputs
    bf16* Xk  = Xq + seg;
    bf16* Xv  = Xk + seg;
    bf16* Qh  = Xv + seg;                        // [bh][l][d], pre-scaled 1/8
    bf16* Kh  = Qh + seg;                        // [bh][s][d]
    bf16* Vh  = Kh + seg;                        // [bh][s][d]
    bf16* Vt  = Xq;                              // alias: Xq dead after qkv_gemm
    bf16* ctx = Vh;                              // alias: Vh dead after transpose

    cvt_kernel<<<8192, 256, 0, stream>>>(w_in, w_out, query, key_, value,
                                         wib, wob, Xq, Xk, Xv);
    qkv_gemm<<<dim3(32, 24), 256, 0, stream>>>(Xq, Xk, Xv, wib, b_in, Qh, Kh, Vh);
    transpose_v<<<dim3(32, 32), 256, 0, stream>>>(Vh, Vt);
    attn_kernel<<<dim3(16, 32), 512, 0, stream>>>(Qh, Kh, Vt, ctx);
    out_gemm<<<dim3(32, 8), 256, 0, stream>>>(ctx, wob, b_out, out);
}

// Round 7
// 238.581 us; speedup vs baseline: 1.3159x; 1.0038x over previous
//
#include <hip/hip_runtime.h>
#include <hip/hip_bf16.h>
#include <stdint.h>

#define L_SEQ 2048
#define S_SEQ 2048
#define BATCH 2
#define EMB 1024
#define NH 16
#define HD 64
#define MROWS 4096  // L*B == S*B

typedef __bf16 bf16x8 __attribute__((ext_vector_type(8)));
typedef float f32x4 __attribute__((ext_vector_type(4)));
typedef __hip_bfloat16 bf16;

__device__ __forceinline__ f32x4 mfma16(bf16x8 a, bf16x8 b, f32x4 c) {
    return __builtin_amdgcn_mfma_f32_16x16x32_bf16(a, b, c, 0, 0, 0);
}

// async global->LDS, 16B per lane. LDS dest = wave-uniform base + lane*16.
__device__ __forceinline__ void gll16(const bf16* g, bf16* l) {
    __builtin_amdgcn_global_load_lds(
        (const __attribute__((address_space(1))) void*)g,
        (__attribute__((address_space(3))) void*)l, 16, 0, 0);
}

// load 8 consecutive fp32, round to bf16, pack into one 16B fragment
__device__ __forceinline__ bf16x8 ld8_cvt(const float* p) {
    const float4 a = *reinterpret_cast<const float4*>(p);
    const float4 b = *reinterpret_cast<const float4*>(p + 4);
    union { bf16x8 v; bf16 h[8]; } u;
    u.h[0] = __float2bfloat16(a.x); u.h[1] = __float2bfloat16(a.y);
    u.h[2] = __float2bfloat16(a.z); u.h[3] = __float2bfloat16(a.w);
    u.h[4] = __float2bfloat16(b.x); u.h[5] = __float2bfloat16(b.y);
    u.h[6] = __float2bfloat16(b.z); u.h[7] = __float2bfloat16(b.w);
    return u.v;
}

// fast pack: two f32 -> bf16x2 via +0x8000 round bias and v_perm_b32 (3 insts)
__device__ __forceinline__ uint32_t packbf2(float a, float b) {
    const uint32_t ra = __float_as_uint(a) + 0x8000u;
    const uint32_t rb = __float_as_uint(b) + 0x8000u;
    return __builtin_amdgcn_perm(rb, ra, 0x07060302u);  // [rb.b3 rb.b2 ra.b3 ra.b2]
}

// ---------------------------------------------------------------------------
// fp32 -> bf16 for w_in, w_out, q, k, v (one memory-bound pass; GEMMs use GLL).
// Regions: [w_in 3M | w_out 1M | q 4M | k 4M | v 4M] = 16,777,216 elems.
// ---------------------------------------------------------------------------
__global__ __launch_bounds__(256) void cvt_kernel(
    const float* __restrict__ w_in, const float* __restrict__ w_out,
    const float* __restrict__ q_in, const float* __restrict__ k_in,
    const float* __restrict__ v_in,
    bf16* __restrict__ wib, bf16* __restrict__ wob,
    bf16* __restrict__ Xq, bf16* __restrict__ Xk, bf16* __restrict__ Xv)
{
    const size_t i = ((size_t)blockIdx.x * 256 + threadIdx.x) * 8;
    const size_t o1 = (size_t)3 * EMB * EMB;        //  3,145,728
    const size_t o2 = o1 + (size_t)EMB * EMB;       //  4,194,304
    const size_t o3 = o2 + (size_t)MROWS * EMB;     //  8,388,608
    const size_t o4 = o3 + (size_t)MROWS * EMB;     // 12,582,912
    const float* src; bf16* dst; size_t j;
    if      (i < o1) { src = w_in;  dst = wib; j = i; }
    else if (i < o2) { src = w_out; dst = wob; j = i - o1; }
    else if (i < o3) { src = q_in;  dst = Xq;  j = i - o2; }
    else if (i < o4) { src = k_in;  dst = Xk;  j = i - o3; }
    else             { src = v_in;  dst = Xv;  j = i - o4; }
    *reinterpret_cast<bf16x8*>(dst + j) = ld8_cvt(src + j);
}

// ---------------------------------------------------------------------------
// Fused QKV projection, pure m97 structure: GLL for A (Xq/Xk/Xv bf16) and
// B (wib bf16). Epilogue: Qh[bh][l][d] (x0.125*log2e), Kh/Vh[bh][s][d].
// 128x128 tile, BK=32, 256 threads.
// ---------------------------------------------------------------------------
__global__ __launch_bounds__(256) void qkv_gemm(
    const bf16* __restrict__ Xq, const bf16* __restrict__ Xk,
    const bf16* __restrict__ Xv, const bf16* __restrict__ wib,
    const float* __restrict__ b_in,
    bf16* __restrict__ Qh, bf16* __restrict__ Kh, bf16* __restrict__ Vh)
{
    __shared__ alignas(16) bf16 lds_a[128 * 32];
    __shared__ alignas(16) bf16 lds_b[128 * 32];

    const int tid  = threadIdx.x;
    const int lane = tid & 63;
    const int wv   = tid >> 6;
    const int quad = lane >> 4;
    const int lx   = lane & 15;

    const int m0  = blockIdx.x * 128;
    const int n0g = blockIdx.y * 128;
    const int chunk = n0g >> 10;              // 0=Q, 1=K, 2=V
    const bf16* Aop = (chunk == 0) ? Xq : (chunk == 1) ? Xk : Xv;

    const int wm = (wv >> 1) * 64;
    const int wn = (wv & 1) * 64;

    // GLL mapping: wave wv, issue i covers rows 16*wv + 64*i + (lane>>2)
    const int gr = 16 * wv + (lane >> 2);
    const int gc = (lane & 3) * 8;
    const bf16* gA = Aop + (size_t)(m0 + gr) * EMB + gc;
    const bf16* gB = wib + (size_t)(n0g + gr) * EMB + gc;
    bf16* lA = lds_a + wv * 512;              // elems; +2048 for issue 1
    bf16* lB = lds_b + wv * 512;

    f32x4 acc[4][4];
#pragma unroll
    for (int i = 0; i < 4; i++)
#pragma unroll
        for (int j = 0; j < 4; j++) acc[i][j] = (f32x4){0.f, 0.f, 0.f, 0.f};

    for (int kt = 0; kt < EMB; kt += 32) {
        __syncthreads();
        gll16(gA + kt, lA);
        gll16(gA + 64 * EMB + kt, lA + 2048);
        gll16(gB + kt, lB);
        gll16(gB + 64 * EMB + kt, lB + 2048);
        __syncthreads();

        bf16x8 af[4], bfv[4];
        const int ka = quad * 8;
#pragma unroll
        for (int sm = 0; sm < 4; sm++)
            af[sm] = *reinterpret_cast<const bf16x8*>(lds_a + (wm + sm * 16 + lx) * 32 + ka);
#pragma unroll
        for (int sn = 0; sn < 4; sn++)
            bfv[sn] = *reinterpret_cast<const bf16x8*>(lds_b + (wn + sn * 16 + lx) * 32 + ka);
#pragma unroll
        for (int sm = 0; sm < 4; sm++)
#pragma unroll
            for (int sn = 0; sn < 4; sn++)
                acc[sm][sn] = mfma16(af[sm], bfv[sn], acc[sm][sn]);
    }

    // Q scale folds 1/sqrt(64) AND log2(e): softmax runs in log2 domain.
    const float scale = (chunk == 0) ? 0.18033688011112042f : 1.0f;
    bf16* dst = (chunk == 0) ? Qh : (chunk == 1) ? Kh : Vh;
#pragma unroll
    for (int sn = 0; sn < 4; sn++) {
        const int n_g = n0g + wn + sn * 16 + lx;
        const float bias = b_in[n_g];
        const int nc = n_g & (EMB - 1);
        const int h  = nc >> 6;
        const int dd = nc & 63;
#pragma unroll
        for (int sm = 0; sm < 4; sm++) {
#pragma unroll
            for (int r = 0; r < 4; r++) {
                const int m_g = m0 + wm + sm * 16 + quad * 4 + r;  // row = l*B + b
                const int t = m_g >> 1;
                const int b = m_g & 1;
                const int bhidx = b * NH + h;
                const float v = (acc[sm][sn][r] + bias) * scale;
                dst[((size_t)bhidx * S_SEQ + t) * HD + dd] = __float2bfloat16(v);
            }
        }
    }
}

// ---------------------------------------------------------------------------
// Vh [bh][s][d] -> Vt [bh][d][s].  64x64 tiles via LDS. grid (32 stiles, 32 bh)
// ---------------------------------------------------------------------------
#define TST 72
__global__ __launch_bounds__(256) void transpose_v(
    const bf16* __restrict__ Vh, bf16* __restrict__ Vt)
{
    __shared__ alignas(16) bf16 t[64 * TST];
    const int tid = threadIdx.x;
    const int bh  = blockIdx.y;
    const int s0  = blockIdx.x * 64;
    const int r0  = tid >> 3;          // 0..31
    const int c0  = (tid & 7) * 8;

    const bf16* src = Vh + (size_t)bh * S_SEQ * HD;
    uint4 a = *reinterpret_cast<const uint4*>(src + (size_t)(s0 + r0) * HD + c0);
    uint4 b = *reinterpret_cast<const uint4*>(src + (size_t)(s0 + r0 + 32) * HD + c0);
    *reinterpret_cast<uint4*>(t + r0 * TST + c0) = a;
    *reinterpret_cast<uint4*>(t + (r0 + 32) * TST + c0) = b;
    __syncthreads();

    const int sc = (tid & 7) * 8;
    bf16* dst = Vt + (size_t)bh * HD * S_SEQ;
#pragma unroll
    for (int half = 0; half < 2; half++) {
        const int d = (tid >> 3) + half * 32;
        union { bf16 h[8]; uint4 u; } o;
#pragma unroll
        for (int j = 0; j < 8; j++) o.h[j] = t[(sc + j) * TST + d];
        *reinterpret_cast<uint4*>(dst + (size_t)d * S_SEQ + s0 + sc) = o.u;
    }
}

// ---------------------------------------------------------------------------
// Flash attention, S^T orientation, log2-domain softmax. Block = (bh, 128 q),
// 8 waves x 16 q, S-tile 128. Next K/V tile prefetched into registers during
// compute. P packed via v_perm; softmax arithmetic vectorized (v_pk_*).
// ---------------------------------------------------------------------------
__global__ __launch_bounds__(512, 4) void attn_kernel(
    const bf16* __restrict__ Qh, const bf16* __restrict__ Kh,
    const bf16* __restrict__ Vt, bf16* __restrict__ ctx)
{
    __shared__ alignas(16) bf16 k_lds[128 * 64];     // [s][d] swizzled
    __shared__ alignas(16) bf16 v_lds[64 * 128];     // [d][s] swizzled
    __shared__ alignas(16) bf16 p_lds[8][16 * 128];  // per-wave [q][s] swizzled

    const int tid  = threadIdx.x;
    const int lane = tid & 63;
    const int wv   = tid >> 6;      // 0..7
    const int quad = lane >> 4;
    const int lx   = lane & 15;
    const int lx7  = lane & 7;

    const int bh = blockIdx.y;
    const int l0 = blockIdx.x * 128;
    const int q0 = wv * 16;

    const bf16* Kbase = Kh + (size_t)bh * S_SEQ * HD;
    const bf16* Vbase = Vt + (size_t)bh * HD * S_SEQ;

    // Q as B-operand: lane holds Q[q0+lx][d = quad*8+j] (scaled by log2e/8)
    const bf16* qrow = Qh + ((size_t)bh * L_SEQ + l0 + q0 + lx) * HD + quad * 8;
    const bf16x8 qf0 = *reinterpret_cast<const bf16x8*>(qrow);
    const bf16x8 qf1 = *reinterpret_cast<const bf16x8*>(qrow + 32);

    float m_run = -1e30f, l_run = 0.f;
    f32x4 accv[4];
#pragma unroll
    for (int sn = 0; sn < 4; sn++) accv[sn] = (f32x4){0.f, 0.f, 0.f, 0.f};

    // staging assignments (512 threads)
    const int kr0 = tid >> 3;             // 0..63 (+64)
    const int kc  = (tid & 7) * 8;
    const int vd0 = tid >> 4;             // 0..31 (+32)
    const int vs  = (tid & 15) * 8;
    const int ksw = (((kc >> 3) ^ (kr0 & 7)) << 3);
    const int vsw = (((vs >> 3) ^ (vd0 & 7)) << 3);

    bf16* p_w = &p_lds[wv][0];

    // prefetch tile 0
    uint4 ka = *reinterpret_cast<const uint4*>(Kbase + (size_t)kr0 * HD + kc);
    uint4 kb = *reinterpret_cast<const uint4*>(Kbase + (size_t)(kr0 + 64) * HD + kc);
    uint4 va = *reinterpret_cast<const uint4*>(Vbase + (size_t)vd0 * S_SEQ + vs);
    uint4 vb = *reinterpret_cast<const uint4*>(Vbase + (size_t)(vd0 + 32) * S_SEQ + vs);

    for (int s0 = 0; s0 < S_SEQ; s0 += 128) {
        __syncthreads();
        *reinterpret_cast<uint4*>(k_lds + kr0 * 64 + ksw) = ka;
        *reinterpret_cast<uint4*>(k_lds + (kr0 + 64) * 64 + ksw) = kb;
        *reinterpret_cast<uint4*>(v_lds + vd0 * 128 + vsw) = va;
        *reinterpret_cast<uint4*>(v_lds + (vd0 + 32) * 128 + vsw) = vb;
        __syncthreads();

        // prefetch next tile (wraps harmlessly on last iter)
        const int s1 = (s0 + 128) & (S_SEQ - 1);
        ka = *reinterpret_cast<const uint4*>(Kbase + (size_t)(s1 + kr0) * HD + kc);
        kb = *reinterpret_cast<const uint4*>(Kbase + (size_t)(s1 + kr0 + 64) * HD + kc);
        va = *reinterpret_cast<const uint4*>(Vbase + (size_t)vd0 * S_SEQ + s1 + vs);
        vb = *reinterpret_cast<const uint4*>(Vbase + (size_t)(vd0 + 32) * S_SEQ + s1 + vs);

        // QK^T transposed: T[s = c*16 + quad*4 + r][q = q0 + lx], log2 domain
        f32x4 sc[8];
#pragma unroll
        for (int c = 0; c < 8; c++) {
            const bf16* kr = k_lds + (c * 16 + lx) * 64;
            bf16x8 kf0 = *reinterpret_cast<const bf16x8*>(kr + ((quad ^ lx7) << 3));
            bf16x8 kf1 = *reinterpret_cast<const bf16x8*>(kr + (((quad + 4) ^ lx7) << 3));
            f32x4 tt = (f32x4){0.f, 0.f, 0.f, 0.f};
            tt = mfma16(kf0, qf0, tt);
            tt = mfma16(kf1, qf1, tt);
            sc[c] = tt;
        }

        // online softmax over s (base-2), per-lane row q=lx
        f32x4 vm = sc[0];
#pragma unroll
        for (int c = 1; c < 8; c++)
#pragma unroll
            for (int r = 0; r < 4; r++) vm[r] = fmaxf(vm[r], sc[c][r]);
        float mloc = fmaxf(fmaxf(vm[0], vm[1]), fmaxf(vm[2], vm[3]));
        mloc = fmaxf(mloc, __shfl_xor(mloc, 16));
        mloc = fmaxf(mloc, __shfl_xor(mloc, 32));
        const float mnew = fmaxf(m_run, mloc);
        const float al = __builtin_amdgcn_exp2f(m_run - mnew);
        m_run = mnew;

        const f32x4 mnew4 = (f32x4){mnew, mnew, mnew, mnew};
        f32x4 rv = (f32x4){0.f, 0.f, 0.f, 0.f};
#pragma unroll
        for (int c = 0; c < 8; c++) {
            f32x4 d = sc[c] - mnew4;   // v_pk_add
#pragma unroll
            for (int r = 0; r < 4; r++) sc[c][r] = __builtin_amdgcn_exp2f(d[r]);
            rv += sc[c];               // v_pk_add
        }
        float rsum = (rv[0] + rv[1]) + (rv[2] + rv[3]);
        rsum += __shfl_xor(rsum, 16);
        rsum += __shfl_xor(rsum, 32);
        l_run = l_run * al + rsum;

        // rescale accumulator rows (O rows are q = quad*4+r)
#pragma unroll
        for (int r = 0; r < 4; r++) {
            const float ar = __shfl(al, quad * 20 + r);  // lane quad*16 + quad*4+r
            const f32x4 ar4 = (f32x4){ar, ar, ar, ar};
            // note: only element r of each accv row belongs to this q; but all
            // lanes of a quad share the same 4 q rows -> scale element-wise:
            // accv[sn][r] *= ar for each r with its own ar.
            (void)ar4;
#pragma unroll
            for (int sn = 0; sn < 4; sn++) accv[sn][r] *= ar;
        }

        // P store: per lane 4 contiguous s per chunk c -> packed b64 (v_perm)
#pragma unroll
        for (int c = 0; c < 8; c++) {
            uint2 pk;
            pk.x = packbf2(sc[c][0], sc[c][1]);
            pk.y = packbf2(sc[c][2], sc[c][3]);
            const int off = lx * 128 + ((((c * 2 + (quad >> 1)) ^ lx7)) << 3) + ((quad & 1) << 2);
            *reinterpret_cast<uint2*>(p_w + off) = pk;
        }

        // PV: O[q][d] += P[q][s] V[s][d]   (per-wave P, no barrier needed)
#pragma unroll
        for (int sk = 0; sk < 4; sk++) {
            bf16x8 pf = *reinterpret_cast<const bf16x8*>(
                p_w + lx * 128 + ((((sk * 4 + quad) ^ lx7)) << 3));
#pragma unroll
            for (int sn = 0; sn < 4; sn++) {
                const bf16* vr = v_lds + (sn * 16 + lx) * 128 + ((((sk * 4 + quad) ^ lx7)) << 3);
                accv[sn] = mfma16(pf, *reinterpret_cast<const bf16x8*>(vr), accv[sn]);
            }
        }
    }

    const int b = bh >> 4;
    const int h = bh & 15;
#pragma unroll
    for (int r = 0; r < 4; r++) {
        const float lr = __shfl(l_run, quad * 20 + r);
        const float inv = 1.f / lr;
        const int l = l0 + q0 + quad * 4 + r;
#pragma unroll
        for (int sn = 0; sn < 4; sn++) {
            const int dd = sn * 16 + lx;
            ctx[(size_t)(l * BATCH + b) * EMB + h * HD + dd] =
                __float2bfloat16(accv[sn][r] * inv);
        }
    }
}

// ---------------------------------------------------------------------------
// Output projection: 64x128 tile -> 512 blocks (2/CU) for cross-block overlap.
// GLL for A (ctx bf16) and B (wob bf16). fp32 out.
// ---------------------------------------------------------------------------
__global__ __launch_bounds__(256) void out_gemm(
    const bf16* __restrict__ ctx, const bf16* __restrict__ wob,
    const float* __restrict__ b_out, float* __restrict__ out)
{
    __shared__ alignas(16) bf16 lds_a[64 * 32];
    __shared__ alignas(16) bf16 lds_b[128 * 32];

    const int tid  = threadIdx.x;
    const int lane = tid & 63;
    const int wv   = tid >> 6;
    const int quad = lane >> 4;
    const int lx   = lane & 15;

    const int m0 = blockIdx.x * 64;
    const int n0 = blockIdx.y * 128;

    const int wm = (wv >> 1) * 32;
    const int wn = (wv & 1) * 64;

    const int gr = 16 * wv + (lane >> 2);
    const int gc = (lane & 3) * 8;
    const bf16* gA = ctx + (size_t)(m0 + gr) * EMB + gc;   // rows 0..63
    const bf16* gB = wob + (size_t)(n0 + gr) * EMB + gc;   // rows 0..63 (+64)
    bf16* lA = lds_a + wv * 512;
    bf16* lB = lds_b + wv * 512;

    f32x4 acc[2][4];
#pragma unroll
    for (int i = 0; i < 2; i++)
#pragma unroll
        for (int j = 0; j < 4; j++) acc[i][j] = (f32x4){0.f, 0.f, 0.f, 0.f};

    for (int kt = 0; kt < EMB; kt += 32) {
        __syncthreads();
        gll16(gA + kt, lA);
        gll16(gB + kt, lB);
        gll16(gB + 64 * EMB + kt, lB + 2048);
        __syncthreads();

        bf16x8 af[2], bfv[4];
        const int ka = quad * 8;
#pragma unroll
        for (int sm = 0; sm < 2; sm++)
            af[sm] = *reinterpret_cast<const bf16x8*>(lds_a + (wm + sm * 16 + lx) * 32 + ka);
#pragma unroll
        for (int sn = 0; sn < 4; sn++)
            bfv[sn] = *reinterpret_cast<const bf16x8*>(lds_b + (wn + sn * 16 + lx) * 32 + ka);
#pragma unroll
        for (int sm = 0; sm < 2; sm++)
#pragma unroll
            for (int sn = 0; sn < 4; sn++)
                acc[sm][sn] = mfma16(af[sm], bfv[sn], acc[sm][sn]);
    }

#pragma unroll
    for (int sn = 0; sn < 4; sn++) {
        const int n_g = n0 + wn + sn * 16 + lx;
        const float bias = b_out[n_g];
#pragma unroll
        for (int sm = 0; sm < 2; sm++) {
#pragma unroll
            for (int r = 0; r < 4; r++) {
                const int m_g = m0 + wm + sm * 16 + quad * 4 + r;
                out[(size_t)m_g * EMB + n_g] = acc[sm][sn][r] + bias;
            }
        }
    }
}

extern "C" void kernel_launch(void* const* d_in, const int* in_sizes, int n_in,
                              void* d_out, int out_size, void* d_ws, size_t ws_size,
                              hipStream_t stream)
{
    const float* query = (const float*)d_in[0];
    const float* key_  = (const float*)d_in[1];
    const float* value = (const float*)d_in[2];
    const float* w_in  = (const float*)d_in[3];
    const float* b_in  = (const float*)d_in[4];
    const float* w_out = (const float*)d_in[5];
    const float* b_out = (const float*)d_in[6];
    float* out = (float*)d_out;

    const size_t seg = (size_t)MROWS * EMB;      // 4,194,304 elems (8 MiB bf16)
    bf16* wib = (bf16*)d_ws;                     // 3*EMB*EMB
    bf16* wob = wib + (size_t)3 * EMB * EMB;     // EMB*EMB
    bf16* Xq  = wob + (size_t)EMB * EMB;         // [m][k] bf16 inputs
    bf16* Xk  = Xq + seg;
    bf16* Xv  = Xk + seg;
    bf16* Qh  = Xv + seg;                        // [bh][l][d], scaled log2e/8
    bf16* Kh  = Qh + seg;                        // [bh][s][d]
    bf16* Vh  = Kh + seg;                        // [bh][s][d]
    bf16* Vt  = Xq;                              // alias: Xq dead after qkv_gemm
    bf16* ctx = Vh;                              // alias: Vh dead after transpose

    cvt_kernel<<<8192, 256, 0, stream>>>(w_in, w_out, query, key_, value,
                                         wib, wob, Xq, Xk, Xv);
    qkv_gemm<<<dim3(32, 24), 256, 0, stream>>>(Xq, Xk, Xv, wib, b_in, Qh, Kh, Vh);
    transpose_v<<<dim3(32, 32), 256, 0, stream>>>(Vh, Vt);
    attn_kernel<<<dim3(16, 32), 512, 0, stream>>>(Qh, Kh, Vt, ctx);
    out_gemm<<<dim3(64, 8), 256, 0, stream>>>(ctx, wob, b_out, out);
}